// Round 1
// baseline (148.511 us; speedup 1.0000x reference)
//
#include <hip/hip_runtime.h>

#define BB 16
#define NN 1024
#define UU 64
#define LALPHA 0.2f
#define MAXD 192

// ---------------- CSR build from dense adjacency ----------------
__global__ void build_csr(const float* __restrict__ adj, int* __restrict__ deg,
                          int* __restrict__ cols) {
    __shared__ int cnt;
    int i = blockIdx.x;
    if (threadIdx.x == 0) cnt = 0;
    __syncthreads();
    for (int j = threadIdx.x; j < NN; j += blockDim.x) {
        if (adj[(size_t)i * NN + j] > 0.0f) {
            int p = atomicAdd(&cnt, 1);
            if (p < MAXD) cols[(size_t)i * MAXD + p] = j;
        }
    }
    __syncthreads();
    if (threadIdx.x == 0) deg[i] = cnt < MAXD ? cnt : MAXD;
}

// ---------------- GEMM: out[m,f] = sum_k concat(A0,A1)[m,k] * W[k,f] ----------------
// A0/A1 each hold 64 columns of the 128-wide concatenated input.
// Block: FOUT*GROUPS threads, handles ROWS_PER_GROUP*GROUPS rows.
template <int FOUT, int RPG, int GROUPS>
__global__ void gemm_concat(const float* __restrict__ A0, const float* __restrict__ A1,
                            const float* __restrict__ W, float* __restrict__ out) {
    const int TR = RPG * GROUPS;
    __shared__ float xs[TR][129];  // +1 pad: groups read different rows same k
    int t = threadIdx.x;
    int f = t % FOUT;
    int rg = t / FOUT;
    int base = blockIdx.x * TR;
    for (int idx = t; idx < TR * 128; idx += FOUT * GROUPS) {
        int r = idx >> 7, c = idx & 127;
        xs[r][c] = (c < 64) ? A0[(size_t)(base + r) * 64 + c]
                            : A1[(size_t)(base + r) * 64 + (c - 64)];
    }
    __syncthreads();
    float acc[RPG];
#pragma unroll
    for (int rr = 0; rr < RPG; rr++) acc[rr] = 0.f;
    for (int k = 0; k < 128; k++) {
        float w = W[(size_t)k * FOUT + f];
#pragma unroll
        for (int rr = 0; rr < RPG; rr++) acc[rr] += xs[rg * RPG + rr][k] * w;
    }
#pragma unroll
    for (int rr = 0; rr < RPG; rr++)
        out[(size_t)(base + rg * RPG + rr) * FOUT + f] = acc[rr];
}

// ---------------- scores: s_src[m] = h[m,:].a[0:F], s_dst[m] = h[m,:].a[F:2F] ----------------
template <int F>
__global__ void score_kernel(const float* __restrict__ h, const float* __restrict__ a,
                             float* __restrict__ s_src, float* __restrict__ s_dst) {
    int m = blockIdx.x, lane = threadIdx.x;
    float ps = 0.f, pd = 0.f;
    for (int f = lane; f < F; f += 64) {
        float hv = h[(size_t)m * F + f];
        ps += hv * a[f];
        pd += hv * a[F + f];
    }
#pragma unroll
    for (int o = 32; o >= 1; o >>= 1) {
        ps += __shfl_xor(ps, o);
        pd += __shfl_xor(pd, o);
    }
    if (lane == 0) {
        s_src[m] = ps;
        s_dst[m] = pd;
    }
}

// ---------------- attention layer 1 (F=128) + sigmoid gates ----------------
__global__ void attn1_kernel(const int* __restrict__ deg, const int* __restrict__ cols,
                             const float* __restrict__ h1, const float* __restrict__ s_src,
                             const float* __restrict__ s_dst, const float* __restrict__ state,
                             float* __restrict__ rstate, float* __restrict__ zbuf) {
    int bi = blockIdx.x;  // b*N + i
    int i = bi & (NN - 1);
    int b = bi >> 10;
    int lane = threadIdx.x;
    int d = deg[i];
    const int* cl = cols + (size_t)i * MAXD;
    float ssrc = s_src[bi];
    __shared__ float w[MAXD];
    float mx = -1e30f;
    for (int j = lane; j < d; j += 64) {
        float e = ssrc + s_dst[b * NN + cl[j]];
        e = e > 0.f ? e : LALPHA * e;
        w[j] = e;
        mx = fmaxf(mx, e);
    }
#pragma unroll
    for (int o = 32; o >= 1; o >>= 1) mx = fmaxf(mx, __shfl_xor(mx, o));
    float sum = 0.f;
    for (int j = lane; j < d; j += 64) {
        float e = __expf(w[j] - mx);
        w[j] = e;
        sum += e;
    }
#pragma unroll
    for (int o = 32; o >= 1; o >>= 1) sum += __shfl_xor(sum, o);
    float inv = 1.f / sum;
    float acc0 = 0.f, acc1 = 0.f;
    for (int j = 0; j < d; j++) {
        float wj = w[j];
        const float* hr = h1 + (size_t)(b * NN + cl[j]) * 128;
        acc0 += wj * hr[lane];
        acc1 += wj * hr[lane + 64];
    }
    float rg = 1.f / (1.f + __expf(-acc0 * inv));
    float zg = 1.f / (1.f + __expf(-acc1 * inv));
    float st = state[(size_t)bi * 64 + lane];
    rstate[(size_t)bi * 64 + lane] = rg * st;
    zbuf[(size_t)bi * 64 + lane] = zg;
}

// ---------------- attention layer 2 (F=64) + tanh + GRU combine ----------------
__global__ void attn2_kernel(const int* __restrict__ deg, const int* __restrict__ cols,
                             const float* __restrict__ h2, const float* __restrict__ s_src,
                             const float* __restrict__ s_dst, const float* __restrict__ state,
                             const float* __restrict__ zbuf, float* __restrict__ out) {
    int bi = blockIdx.x;
    int i = bi & (NN - 1);
    int b = bi >> 10;
    int lane = threadIdx.x;
    int d = deg[i];
    const int* cl = cols + (size_t)i * MAXD;
    float ssrc = s_src[bi];
    __shared__ float w[MAXD];
    float mx = -1e30f;
    for (int j = lane; j < d; j += 64) {
        float e = ssrc + s_dst[b * NN + cl[j]];
        e = e > 0.f ? e : LALPHA * e;
        w[j] = e;
        mx = fmaxf(mx, e);
    }
#pragma unroll
    for (int o = 32; o >= 1; o >>= 1) mx = fmaxf(mx, __shfl_xor(mx, o));
    float sum = 0.f;
    for (int j = lane; j < d; j += 64) {
        float e = __expf(w[j] - mx);
        w[j] = e;
        sum += e;
    }
#pragma unroll
    for (int o = 32; o >= 1; o >>= 1) sum += __shfl_xor(sum, o);
    float inv = 1.f / sum;
    float acc = 0.f;
    for (int j = 0; j < d; j++) {
        acc += w[j] * h2[(size_t)(b * NN + cl[j]) * 64 + lane];
    }
    float ht = tanhf(acc * inv);
    float z = zbuf[(size_t)bi * 64 + lane];
    float st = state[(size_t)bi * 64 + lane];
    out[(size_t)bi * 64 + lane] = z * st + (1.f - z) * ht;
}

extern "C" void kernel_launch(void* const* d_in, const int* in_sizes, int n_in,
                              void* d_out, int out_size, void* d_ws, size_t ws_size,
                              hipStream_t stream) {
    const float* X     = (const float*)d_in[0];
    const float* state = (const float*)d_in[1];
    const float* adj   = (const float*)d_in[2];
    const float* W1    = (const float*)d_in[3];
    const float* a1    = (const float*)d_in[4];
    const float* W2    = (const float*)d_in[5];
    const float* a2    = (const float*)d_in[6];
    float* out = (float*)d_out;

    char* ws = (char*)d_ws;
    size_t off = 0;
    auto alloc = [&](size_t bytes) -> void* {
        void* p = ws + off;
        off = (off + bytes + 255) & ~(size_t)255;
        return p;
    };
    int*   deg    = (int*)alloc(NN * sizeof(int));
    int*   cols   = (int*)alloc((size_t)NN * MAXD * sizeof(int));
    float* h1     = (float*)alloc((size_t)BB * NN * 128 * sizeof(float));
    float* ssrc1  = (float*)alloc((size_t)BB * NN * sizeof(float));
    float* sdst1  = (float*)alloc((size_t)BB * NN * sizeof(float));
    float* rstate = (float*)alloc((size_t)BB * NN * 64 * sizeof(float));
    float* zbuf   = (float*)alloc((size_t)BB * NN * 64 * sizeof(float));
    float* h2     = (float*)alloc((size_t)BB * NN * 64 * sizeof(float));
    float* ssrc2  = (float*)alloc((size_t)BB * NN * sizeof(float));
    float* sdst2  = (float*)alloc((size_t)BB * NN * sizeof(float));

    const int M = BB * NN;  // 16384 rows

    build_csr<<<NN, 256, 0, stream>>>(adj, deg, cols);
    gemm_concat<128, 8, 2><<<M / 16, 256, 0, stream>>>(X, state, W1, h1);
    score_kernel<128><<<M, 64, 0, stream>>>(h1, a1, ssrc1, sdst1);
    attn1_kernel<<<M, 64, 0, stream>>>(deg, cols, h1, ssrc1, sdst1, state, rstate, zbuf);
    gemm_concat<64, 4, 4><<<M / 16, 256, 0, stream>>>(X, rstate, W2, h2);
    score_kernel<64><<<M, 64, 0, stream>>>(h2, a2, ssrc2, sdst2);
    attn2_kernel<<<M, 64, 0, stream>>>(deg, cols, h2, ssrc2, sdst2, state, zbuf, out);
}

// Round 2
// 141.883 us; speedup vs baseline: 1.0467x; 1.0467x over previous
//
#include <hip/hip_runtime.h>

#define BB 16
#define NN 1024
#define LALPHA 0.2f
#define MAXD 192

// ---------------- CSR build from dense adjacency ----------------
__global__ void build_csr(const float* __restrict__ adj, int* __restrict__ deg,
                          int* __restrict__ cols) {
    __shared__ int cnt;
    int i = blockIdx.x;
    if (threadIdx.x == 0) cnt = 0;
    __syncthreads();
    for (int j = threadIdx.x; j < NN; j += blockDim.x) {
        if (adj[(size_t)i * NN + j] > 0.0f) {
            int p = atomicAdd(&cnt, 1);
            if (p < MAXD) cols[(size_t)i * MAXD + p] = j;
        }
    }
    __syncthreads();
    if (threadIdx.x == 0) deg[i] = cnt < MAXD ? cnt : MAXD;
}

// ---------------- fused GEMM + attention-score epilogue ----------------
// h[m,f] = sum_k concat(A0,A1)[m,k] * W[k,f]   (k = 128)
// s_src[m] = h[m,:] . avec[0:FOUT], s_dst[m] = h[m,:] . avec[FOUT:2FOUT]
// Thread owns 4 rows x 4 cols. TFN = FOUT/4 threads per row-group (contiguous lanes).
template <int FOUT, int RB>
__global__ void gemm_score(const float* __restrict__ A0, const float* __restrict__ A1,
                           const float* __restrict__ W, const float* __restrict__ avec,
                           float* __restrict__ h, float* __restrict__ s_src,
                           float* __restrict__ s_dst) {
    constexpr int TFN = FOUT / 4;
    constexpr int NT = (RB / 4) * TFN;  // block size
    __shared__ float xs[RB][132];
    int t = threadIdx.x;
    int tf = t % TFN, tr = t / TFN;
    int f0 = tf * 4, r0 = tr * 4;
    int base = blockIdx.x * RB;

    // stage x tile (concatenated 128-wide rows) via float4
    for (int idx = t; idx < RB * 32; idx += NT) {
        int r = idx >> 5, c = (idx & 31) * 4;
        float4 v = (c < 64) ? *(const float4*)(A0 + (size_t)(base + r) * 64 + c)
                            : *(const float4*)(A1 + (size_t)(base + r) * 64 + (c - 64));
        xs[r][c] = v.x; xs[r][c + 1] = v.y; xs[r][c + 2] = v.z; xs[r][c + 3] = v.w;
    }
    __syncthreads();

    float acc[4][4] = {};
    for (int k = 0; k < 128; k += 4) {
        float4 xv[4], wv[4];
#pragma unroll
        for (int i = 0; i < 4; i++) xv[i] = *(const float4*)&xs[r0 + i][k];
#pragma unroll
        for (int i = 0; i < 4; i++) wv[i] = *(const float4*)(W + (size_t)(k + i) * FOUT + f0);
#pragma unroll
        for (int i = 0; i < 4; i++) {
            float xr[4] = {xv[i].x, xv[i].y, xv[i].z, xv[i].w};
#pragma unroll
            for (int kk = 0; kk < 4; kk++) {
                acc[i][0] += xr[kk] * wv[kk].x;
                acc[i][1] += xr[kk] * wv[kk].y;
                acc[i][2] += xr[kk] * wv[kk].z;
                acc[i][3] += xr[kk] * wv[kk].w;
            }
        }
    }

    float a_s[4], a_d[4];
#pragma unroll
    for (int i = 0; i < 4; i++) {
        a_s[i] = avec[f0 + i];
        a_d[i] = avec[FOUT + f0 + i];
    }
#pragma unroll
    for (int i = 0; i < 4; i++) {
        int m = base + r0 + i;
        *(float4*)(h + (size_t)m * FOUT + f0) =
            make_float4(acc[i][0], acc[i][1], acc[i][2], acc[i][3]);
        float ps = acc[i][0] * a_s[0] + acc[i][1] * a_s[1] + acc[i][2] * a_s[2] + acc[i][3] * a_s[3];
        float pd = acc[i][0] * a_d[0] + acc[i][1] * a_d[1] + acc[i][2] * a_d[2] + acc[i][3] * a_d[3];
#pragma unroll
        for (int o = TFN / 2; o >= 1; o >>= 1) {
            ps += __shfl_xor(ps, o);
            pd += __shfl_xor(pd, o);
        }
        if (tf == 0) {
            s_src[m] = ps;
            s_dst[m] = pd;
        }
    }
}

// ---------------- attention layer 1 (F=128) + sigmoid gates ----------------
__global__ void attn1_kernel(const int* __restrict__ deg, const int* __restrict__ cols,
                             const float* __restrict__ h1, const float* __restrict__ s_src,
                             const float* __restrict__ s_dst, const float* __restrict__ state,
                             float* __restrict__ rstate, float* __restrict__ zbuf) {
    int bi = blockIdx.x;
    int i = bi & (NN - 1);
    int b = bi >> 10;
    int lane = threadIdx.x;
    int d = deg[i];
    float ssrc = s_src[bi];
    __shared__ float w[MAXD];
    __shared__ int cl[MAXD];
    for (int j = lane; j < d; j += 64) cl[j] = cols[(size_t)i * MAXD + j];
    __syncthreads();
    float mx = -1e30f;
    for (int j = lane; j < d; j += 64) {
        float e = ssrc + s_dst[b * NN + cl[j]];
        e = e > 0.f ? e : LALPHA * e;
        w[j] = e;
        mx = fmaxf(mx, e);
    }
#pragma unroll
    for (int o = 32; o >= 1; o >>= 1) mx = fmaxf(mx, __shfl_xor(mx, o));
    float sum = 0.f;
    for (int j = lane; j < d; j += 64) {
        float e = __expf(w[j] - mx);
        w[j] = e;
        sum += e;
    }
#pragma unroll
    for (int o = 32; o >= 1; o >>= 1) sum += __shfl_xor(sum, o);
    __syncthreads();
    float inv = 1.f / sum;
    float acc0 = 0.f, acc1 = 0.f;
    int j = 0;
    for (; j + 1 < d; j += 2) {
        float w0 = w[j], w1 = w[j + 1];
        const float* p0 = h1 + (size_t)(b * NN + cl[j]) * 128;
        const float* p1 = h1 + (size_t)(b * NN + cl[j + 1]) * 128;
        float x0 = p0[lane], y0 = p0[lane + 64];
        float x1 = p1[lane], y1 = p1[lane + 64];
        acc0 += w0 * x0 + w1 * x1;
        acc1 += w0 * y0 + w1 * y1;
    }
    if (j < d) {
        float w0 = w[j];
        const float* p0 = h1 + (size_t)(b * NN + cl[j]) * 128;
        acc0 += w0 * p0[lane];
        acc1 += w0 * p0[lane + 64];
    }
    float rg = 1.f / (1.f + __expf(-acc0 * inv));
    float zg = 1.f / (1.f + __expf(-acc1 * inv));
    float st = state[(size_t)bi * 64 + lane];
    rstate[(size_t)bi * 64 + lane] = rg * st;
    zbuf[(size_t)bi * 64 + lane] = zg;
}

// ---------------- attention layer 2 (F=64) + tanh + GRU combine ----------------
__global__ void attn2_kernel(const int* __restrict__ deg, const int* __restrict__ cols,
                             const float* __restrict__ h2, const float* __restrict__ s_src,
                             const float* __restrict__ s_dst, const float* __restrict__ state,
                             const float* __restrict__ zbuf, float* __restrict__ out) {
    int bi = blockIdx.x;
    int i = bi & (NN - 1);
    int b = bi >> 10;
    int lane = threadIdx.x;
    int d = deg[i];
    float ssrc = s_src[bi];
    __shared__ float w[MAXD];
    __shared__ int cl[MAXD];
    for (int j = lane; j < d; j += 64) cl[j] = cols[(size_t)i * MAXD + j];
    __syncthreads();
    float mx = -1e30f;
    for (int j = lane; j < d; j += 64) {
        float e = ssrc + s_dst[b * NN + cl[j]];
        e = e > 0.f ? e : LALPHA * e;
        w[j] = e;
        mx = fmaxf(mx, e);
    }
#pragma unroll
    for (int o = 32; o >= 1; o >>= 1) mx = fmaxf(mx, __shfl_xor(mx, o));
    float sum = 0.f;
    for (int j = lane; j < d; j += 64) {
        float e = __expf(w[j] - mx);
        w[j] = e;
        sum += e;
    }
#pragma unroll
    for (int o = 32; o >= 1; o >>= 1) sum += __shfl_xor(sum, o);
    __syncthreads();
    float inv = 1.f / sum;
    float acc = 0.f;
    int j = 0;
    for (; j + 1 < d; j += 2) {
        float w0 = w[j], w1 = w[j + 1];
        const float* p0 = h2 + (size_t)(b * NN + cl[j]) * 64;
        const float* p1 = h2 + (size_t)(b * NN + cl[j + 1]) * 64;
        acc += w0 * p0[lane] + w1 * p1[lane];
    }
    if (j < d) acc += w[j] * h2[(size_t)(b * NN + cl[j]) * 64 + lane];
    float ht = tanhf(acc * inv);
    float z = zbuf[(size_t)bi * 64 + lane];
    float st = state[(size_t)bi * 64 + lane];
    out[(size_t)bi * 64 + lane] = z * st + (1.f - z) * ht;
}

extern "C" void kernel_launch(void* const* d_in, const int* in_sizes, int n_in,
                              void* d_out, int out_size, void* d_ws, size_t ws_size,
                              hipStream_t stream) {
    const float* X     = (const float*)d_in[0];
    const float* state = (const float*)d_in[1];
    const float* adj   = (const float*)d_in[2];
    const float* W1    = (const float*)d_in[3];
    const float* a1    = (const float*)d_in[4];
    const float* W2    = (const float*)d_in[5];
    const float* a2    = (const float*)d_in[6];
    float* out = (float*)d_out;

    char* ws = (char*)d_ws;
    size_t off = 0;
    auto alloc = [&](size_t bytes) -> void* {
        void* p = ws + off;
        off = (off + bytes + 255) & ~(size_t)255;
        return p;
    };
    int*   deg    = (int*)alloc(NN * sizeof(int));
    int*   cols   = (int*)alloc((size_t)NN * MAXD * sizeof(int));
    float* h1     = (float*)alloc((size_t)BB * NN * 128 * sizeof(float));
    float* ssrc1  = (float*)alloc((size_t)BB * NN * sizeof(float));
    float* sdst1  = (float*)alloc((size_t)BB * NN * sizeof(float));
    float* rstate = (float*)alloc((size_t)BB * NN * 64 * sizeof(float));
    float* zbuf   = (float*)alloc((size_t)BB * NN * 64 * sizeof(float));
    float* h2     = (float*)alloc((size_t)BB * NN * 64 * sizeof(float));
    float* ssrc2  = (float*)alloc((size_t)BB * NN * sizeof(float));
    float* sdst2  = (float*)alloc((size_t)BB * NN * sizeof(float));

    const int M = BB * NN;  // 16384 rows

    build_csr<<<NN, 256, 0, stream>>>(adj, deg, cols);
    // FOUT=128, RB=32 -> 256 threads, grid 512
    gemm_score<128, 32><<<M / 32, 256, 0, stream>>>(X, state, W1, a1, h1, ssrc1, sdst1);
    attn1_kernel<<<M, 64, 0, stream>>>(deg, cols, h1, ssrc1, sdst1, state, rstate, zbuf);
    // FOUT=64, RB=64 -> 256 threads, grid 256
    gemm_score<64, 64><<<M / 64, 256, 0, stream>>>(X, rstate, W2, a2, h2, ssrc2, sdst2);
    attn2_kernel<<<M, 64, 0, stream>>>(deg, cols, h2, ssrc2, sdst2, state, zbuf, out);
}